// Round 1
// baseline (424.709 us; speedup 1.0000x reference)
//
#include <hip/hip_runtime.h>
#include <math.h>

// E8 lattice quantizer: E8 = D8 ∪ (D8 + 1/2).
// Per row of 8 floats: quantize against both cosets, keep the nearer point
// (y2 only on strict win, matching torch.argmin tie -> index 0).
//
// D8 quantize: f = rint(x); if sum(f) is odd, nudge the coordinate with the
// largest |x - f| by sign(x - f) (+1 on exact-zero delta). This is the
// parity-folded equivalent of the reference's f/g selection:
//   g = f ± 1 at one coord  =>  sum(g) even  <=>  sum(f) odd.

__device__ __forceinline__ void d8_quant(const float x[8], float out[8]) {
#pragma clang fp contract(off)
    float f[8], d[8];
#pragma unroll
    for (int j = 0; j < 8; ++j) {
        f[j] = rintf(x[j]);          // round-half-to-even, == jnp.round
        d[j] = x[j] - f[j];
    }
    // argmax |d|, FIRST index wins ties (strict > replaces)
    int k = 0;
    float best = fabsf(d[0]);
    float dk = d[0];
#pragma unroll
    for (int j = 1; j < 8; ++j) {
        float a = fabsf(d[j]);
        bool gt = a > best;
        best = gt ? a : best;
        dk   = gt ? d[j] : dk;
        k    = gt ? j : k;
    }
    float fix = (dk < 0.0f) ? -1.0f : 1.0f;   // dk==0 -> +1, matches where(dk<0,-1,1)
    float sumf = 0.0f;
#pragma unroll
    for (int j = 0; j < 8; ++j) sumf += f[j]; // exact: small integers
    int si = (int)sumf;                        // (-3)&1 == 1, parity OK for negatives
    float add = (si & 1) ? fix : 0.0f;
#pragma unroll
    for (int j = 0; j < 8; ++j) out[j] = f[j] + ((j == k) ? add : 0.0f);
}

__global__ __launch_bounds__(256) void e8_quant_kernel(
    const float4* __restrict__ in, float4* __restrict__ out, int nrows)
{
#pragma clang fp contract(off)
    int i = blockIdx.x * blockDim.x + threadIdx.x;
    if (i >= nrows) return;

    float4 a = in[2 * i];
    float4 b = in[2 * i + 1];
    float x[8] = {a.x, a.y, a.z, a.w, b.x, b.y, b.z, b.w};

    float y1[8], y2[8], t[8];
    d8_quant(x, y1);
#pragma unroll
    for (int j = 0; j < 8; ++j) t[j] = x[j] - 0.5f;
    d8_quant(t, y2);
#pragma unroll
    for (int j = 0; j < 8; ++j) y2[j] += 0.5f;

    // Distances: sequential sum of squares, no FMA contraction (matches np),
    // then sqrt so tie behavior matches jnp.linalg.norm comparison exactly.
    float s1 = 0.0f, s2 = 0.0f;
#pragma unroll
    for (int j = 0; j < 8; ++j) { float e = x[j] - y1[j]; s1 += e * e; }
#pragma unroll
    for (int j = 0; j < 8; ++j) { float e = x[j] - y2[j]; s2 += e * e; }
    bool take2 = sqrtf(s2) < sqrtf(s1);   // strict: ties keep y1

#pragma unroll
    for (int j = 0; j < 8; ++j) x[j] = take2 ? y2[j] : y1[j];

    out[2 * i]     = make_float4(x[0], x[1], x[2], x[3]);
    out[2 * i + 1] = make_float4(x[4], x[5], x[6], x[7]);
}

extern "C" void kernel_launch(void* const* d_in, const int* in_sizes, int n_in,
                              void* d_out, int out_size, void* d_ws, size_t ws_size,
                              hipStream_t stream) {
    const float* x = (const float*)d_in[0];
    float* o = (float*)d_out;
    int nrows = in_sizes[0] / 8;
    const int block = 256;
    const int grid = (nrows + block - 1) / block;
    e8_quant_kernel<<<grid, block, 0, stream>>>(
        (const float4*)x, (float4*)o, nrows);
}

// Round 2
// 411.311 us; speedup vs baseline: 1.0326x; 1.0326x over previous
//
#include <hip/hip_runtime.h>
#include <math.h>

// E8 lattice quantizer, pair-cooperative layout.
// E8 = D8 ∪ (D8 + 1/2); per 8-float row quantize against both cosets, keep
// the nearer (y2 only on STRICT win).
//
// Layout: one thread per float4 (half-row). Lane l loads float4[l] -> every
// load/store instruction is perfectly coalesced (16 B lane stride). Lanes
// (2j, 2j+1) of a wave cooperate on row j via __shfl_xor(.,1).
//
// Exactness invariants (validated absmax==0.0 in round 1's sequential kernel):
//  - rintf == jnp.round (half-to-even)
//  - parity shortcut: g = f±1 at one coord => sum(g) even <=> sum(f) odd
//  - argmax FIRST index wins ties: local scans use strict >, cross-lane tie
//    goes to the low lane (its indices 0..3 precede the hi lane's 4..7)
//  - distance sum in exact left-to-right order: low lane computes the
//    e0²..e3² prefix, hi lane continues with e4²..e7², no FMA contraction.

__device__ __forceinline__ float sx1(float v) { return __shfl_xor(v, 1, 64); }

__global__ __launch_bounds__(256) void e8_quant_pair(
    const float4* __restrict__ in, float4* __restrict__ out, int n4)
{
#pragma clang fp contract(off)
    int t = blockIdx.x * blockDim.x + threadIdx.x;
    if (t >= n4) return;
    const bool hi = (t & 1) != 0;   // hi lane holds coords 4..7 of its row

    float4 v = in[t];
    float x[4] = {v.x, v.y, v.z, v.w};

    float y[2][4];
#pragma unroll
    for (int c = 0; c < 2; ++c) {
        const float h = c ? 0.5f : 0.0f;
        float f[4], d[4];
#pragma unroll
        for (int j = 0; j < 4; ++j) {
            float xc = x[j] - h;          // exact (0.5 exact), same op as ref
            f[j] = rintf(xc);             // round-half-to-even
            d[j] = xc - f[j];             // exact (Sterbenz-ish small values)
        }
        // local argmax |d|, first index wins (strict > replaces)
        float best = fabsf(d[0]); float dk = d[0]; int k = 0;
#pragma unroll
        for (int j = 1; j < 4; ++j) {
            float a = fabsf(d[j]);
            bool gt = a > best;
            best = gt ? a : best; dk = gt ? d[j] : dk; k = gt ? j : k;
        }
        float ls = ((f[0] + f[1]) + f[2]) + f[3];   // exact small integers
        float obest = sx1(best);
        float osum  = sx1(ls);
        // global winner: low lane wins ties (global first index)
        bool win = hi ? (best > obest) : (best >= obest);
        float tot = ls + osum;                       // exact
        int par = ((int)tot) & 1;                    // C trunc keeps parity for negatives
        float fix = (dk < 0.0f) ? -1.0f : 1.0f;      // dk==0 -> +1 (matches ref)
        float add = (win && par) ? fix : 0.0f;
#pragma unroll
        for (int j = 0; j < 4; ++j)
            y[c][j] = (f[j] + ((j == k) ? add : 0.0f)) + h;  // +h exact (ints + 0.5)
    }

    // distance sums, exact reference (left-to-right) association
    float s[2];
#pragma unroll
    for (int c = 0; c < 2; ++c) {
        float eq[4];
#pragma unroll
        for (int j = 0; j < 4; ++j) { float e = x[j] - y[c][j]; eq[j] = e * e; }
        // low-lane prefix in order e0,e1,e2,e3 (0+e0 == e0 exact)
        float pl = (((0.0f + eq[0]) + eq[1]) + eq[2]) + eq[3];
        float q = sx1(pl);                    // hi lane receives low's prefix
        float th = (((q + eq[0]) + eq[1]) + eq[2]) + eq[3];  // hi: +e4²..e7² in order
        float r = sx1(th);                    // low lane receives hi's total
        s[c] = hi ? th : r;                   // both lanes: exact sequential total
    }

    bool take2 = sqrtf(s[1]) < sqrtf(s[0]);   // strict: ties keep y1

    float4 o;
    o.x = take2 ? y[1][0] : y[0][0];
    o.y = take2 ? y[1][1] : y[0][1];
    o.z = take2 ? y[1][2] : y[0][2];
    o.w = take2 ? y[1][3] : y[0][3];
    out[t] = o;
}

extern "C" void kernel_launch(void* const* d_in, const int* in_sizes, int n_in,
                              void* d_out, int out_size, void* d_ws, size_t ws_size,
                              hipStream_t stream) {
    const float4* x = (const float4*)d_in[0];
    float4* o = (float4*)d_out;
    int n4 = in_sizes[0] / 4;                 // one thread per float4 (half-row)
    const int block = 256;
    const int grid = (n4 + block - 1) / block;
    e8_quant_pair<<<grid, block, 0, stream>>>(x, o, n4);
}